// Round 16
// baseline (239.358 us; speedup 1.0000x reference)
//
#include <hip/hip_runtime.h>
#include <hip/hip_bf16.h>

#define N_NODES 20000
#define N_EDGES 320000
#define NG 16

using bf16 = __hip_bfloat16;
typedef __attribute__((ext_vector_type(8))) short short8v;
typedef __attribute__((ext_vector_type(4))) short short4v;
typedef __attribute__((ext_vector_type(4))) float f32x4;

static __device__ __forceinline__ short f2bs(float f) {
  bf16 h = __float2bfloat16(f);
  union { bf16 b; short s; } u;
  u.b = h;
  return u.s;
}
static __device__ __forceinline__ float bs2f(short s) {
  union { short s; bf16 b; } u;
  u.s = s;
  return __bfloat162float(u.b);
}

// ---------------------------------------------------------------------------
// K_prep: globals matmuls, weight bf16 cvt (pi for We2b; pi on first 256
// k-cols of Wb_n2), node_feats -> nfb.
__global__ __launch_bounds__(256) void k_prep(
    const float* __restrict__ globals_, const float* __restrict__ Wg2,
    const float* __restrict__ Wng2, const float* __restrict__ Wgg,
    const float* __restrict__ bg, float* __restrict__ g2e,
    float* __restrict__ g2n, float* __restrict__ gg,
    const float* __restrict__ We1, const float* __restrict__ Wn1,
    const float* __restrict__ Win1, const float* __restrict__ We2,
    const float* __restrict__ Wn2, const float* __restrict__ Win2,
    bf16* __restrict__ Wb_e1, bf16* __restrict__ Wb_n1,
    bf16* __restrict__ Wb_e2, bf16* __restrict__ Wb_n2,
    const float* __restrict__ nf, bf16* __restrict__ nfb) {
  int idx = blockIdx.x * 256 + threadIdx.x;
  if (idx < 6144) {
    int arr = idx >> 11;
    int rem = idx & 2047;
    int g = rem >> 7, c = rem & 127;
    const float* W = arr == 0 ? Wg2 : (arr == 1 ? Wng2 : Wgg);
    float acc = (arr == 2) ? bg[c] : 0.f;
#pragma unroll
    for (int k = 0; k < 16; ++k) acc += globals_[g * 16 + k] * W[c * 16 + k];
    float* o = arr == 0 ? g2e : (arr == 1 ? g2n : gg);
    o[rem] = acc;
    return;
  }
  idx -= 6144;
  if (idx < 172032) {
    int i = idx;
    float v;
    bf16* dst;
    int di;
    if (i < 8192) {
      v = We1[i]; dst = Wb_e1; di = i;
    } else if (i < 90112) {
      int j = i - 8192, r = j / 320, c = j % 320;
      v = c < 64 ? Wn1[r * 64 + c] : Win1[r * 256 + (c - 64)];
      dst = Wb_n1; di = j;
    } else if (i < 122880) {
      int j = i - 90112;
      int n = j >> 8, p = j & 255;
      int k = ((p & 15) << 4) | (p >> 4);  // pi (self-inverse 16x16 transpose)
      v = We2[n * 256 + k];
      dst = Wb_e2; di = j;
    } else {
      int j = i - 122880, r = j / 384, c = j % 384;
      if (c < 256) {
        int k = ((c & 15) << 4) | (c >> 4);  // pi on n1 k-axis
        v = Wn2[r * 256 + k];
      } else {
        v = Win2[r * 128 + (c - 256)];
      }
      dst = Wb_n2; di = j;
    }
    dst[di] = __float2bfloat16(v);
    return;
  }
  idx -= 172032;
  if (idx < 320000) {
    int n = idx >> 4, q = idx & 15;
    float4 v = *(const float4*)(nf + (size_t)n * 64 + q * 4);
    short4v o = {f2bs(v.x), f2bs(v.y), f2bs(v.z), f2bs(v.w)};
    *(short4v*)((short*)nfb + (size_t)n * 64 + q * 4) = o;
  }
}

// ---------------------------------------------------------------------------
// K1: counts.
__global__ __launch_bounds__(256) void k_counts(
    const int* __restrict__ recv, const int* __restrict__ node_graph,
    int* __restrict__ cnt_node, int* __restrict__ node_cnt_g,
    int* __restrict__ edge_cnt_g) {
  __shared__ int le[NG], ln[NG];
  int tid = threadIdx.x;
  if (tid < NG) { le[tid] = 0; ln[tid] = 0; }
  __syncthreads();
  int idx = blockIdx.x * 256 + tid;
  if (idx < N_EDGES) {
    int r = recv[idx];
    atomicAdd(&cnt_node[r], 1);
    atomicAdd(&le[node_graph[r]], 1);
  } else if (idx < N_EDGES + N_NODES) {
    int n = idx - N_EDGES;
    atomicAdd(&ln[node_graph[n]], 1);
  }
  __syncthreads();
  if (tid < NG && le[tid]) atomicAdd(&edge_cnt_g[tid], le[tid]);
  if (tid >= NG && tid < 2 * NG && ln[tid - NG]) atomicAdd(&node_cnt_g[tid - NG], ln[tid - NG]);
}

// ---------------------------------------------------------------------------
// K1b: exclusive prefix sum (shuffle-based, 1024 elems/iter).
__global__ __launch_bounds__(256) void k_scan(const int* __restrict__ cnt,
                                              int* __restrict__ offset,
                                              int* __restrict__ cursor) {
  __shared__ int wsum[4];
  __shared__ int carry_s;
  int tid = threadIdx.x, lane = tid & 63, wv = tid >> 6;
  if (tid == 0) carry_s = 0;
  __syncthreads();
  for (int base = 0; base < N_NODES; base += 1024) {
    int idx = base + tid * 4;
    int v[4];
    int s = 0;
#pragma unroll
    for (int i = 0; i < 4; ++i) {
      v[i] = (idx + i < N_NODES) ? cnt[idx + i] : 0;
      s += v[i];
    }
    int ps = s;
#pragma unroll
    for (int d = 1; d < 64; d <<= 1) {
      int t = __shfl_up(ps, d, 64);
      if (lane >= d) ps += t;
    }
    if (lane == 63) wsum[wv] = ps;
    __syncthreads();
    int wbase = carry_s;
    for (int w2 = 0; w2 < wv; ++w2) wbase += wsum[w2];
    int run = wbase + ps - s;
#pragma unroll
    for (int i = 0; i < 4; ++i) {
      if (idx + i < N_NODES) {
        offset[idx + i] = run;
        cursor[idx + i] = 0;
      }
      run += v[i];
    }
    __syncthreads();
    if (tid == 0) carry_s += wsum[0] + wsum[1] + wsum[2] + wsum[3];
    __syncthreads();
  }
  if (tid == 0) offset[N_NODES] = carry_s;
}

// ---------------------------------------------------------------------------
// K1c: scatter edges into CSR positions.
__global__ __launch_bounds__(256) void k_scatter(
    const int* __restrict__ recv, const int* __restrict__ offset,
    int* __restrict__ cursor, int* __restrict__ pos2edge,
    int* __restrict__ pos2node) {
  int e = blockIdx.x * 256 + threadIdx.x;
  if (e >= N_EDGES) return;
  int n = recv[e];
  int slot = atomicAdd(&cursor[n], 1);
  int pos = offset[n] + slot;
  pos2edge[pos] = e;
  pos2node[pos] = n;
}

// ---------------------------------------------------------------------------
// FUSED edge pipeline (v10 = v9 + PERSISTENT blocks w/ cross-tile pipeline):
//   grid = 1000 blocks (all co-resident at 4/CU), 5 consecutive tiles each.
//   Next tile's meta + pos2edge + edge_feats gathers are issued during the
//   current tile's agg1/e2 phases (register handoff); wreg refill schedule
//   rotates so next tile's We2 chunk-0 loads during chunk-3's MFMA.
//   Meta arrays parity-double-buffered; barrier #0 protects t16 reuse.
__global__ __launch_bounds__(256, 4) void k_edge(
    const float* __restrict__ edge_feats, const bf16* __restrict__ We1b,
    const bf16* __restrict__ We2b, const float* __restrict__ be1,
    const float* __restrict__ be2, const float* __restrict__ g2e,
    const int* __restrict__ pos2edge, const int* __restrict__ pos2node,
    const int* __restrict__ node_graph, const int* __restrict__ offset,
    float* __restrict__ agg1f, float* __restrict__ agg2f) {
  __shared__ __align__(16) short t16[64 * 264];  // 33792B multiplexed
  __shared__ int rownode_s[2][64];
  __shared__ int rowgid_s[2][64];
  char* tb = (char*)t16;
  const int tid = threadIdx.x;
  const int wave = tid >> 6, lane = tid & 63;
  const int l15 = lane & 15, grp = lane >> 4;
  const int base = wave * 16;
  const int n0w = tid >> 3, cgw = tid & 7;

  // ---- prologue: prefetch tile 0 meta + A1 + We2 chunk 0
  int rn_next = 0, rg_next = 0;
  short8v a1_next;
  short8v wreg[4];
  {
    const int tile0 = blockIdx.x * 5;
    if (tid < 64) {
      rn_next = pos2node[tile0 * 64 + tid];
      rg_next = node_graph[rn_next];
    }
    int e0 = pos2edge[tile0 * 64 + base + l15];
    const float* er = edge_feats + (size_t)e0 * 32 + grp * 8;
    float4 a = *(const float4*)er;
    float4 b = *(const float4*)(er + 4);
    a1_next[0] = f2bs(a.x); a1_next[1] = f2bs(a.y);
    a1_next[2] = f2bs(a.z); a1_next[3] = f2bs(a.w);
    a1_next[4] = f2bs(b.x); a1_next[5] = f2bs(b.y);
    a1_next[6] = f2bs(b.z); a1_next[7] = f2bs(b.w);
#pragma unroll
    for (int s = 0; s < 4; ++s)
      wreg[s] = *(const short8v*)((const short*)We2b + (size_t)(n0w + s * 32) * 256 + cgw * 8);
  }

#pragma unroll 1
  for (int t = 0; t < 5; ++t) {
    const int tile = blockIdx.x * 5 + t;
    const int p0 = tile * 64;
    const int pr = t & 1;
    __syncthreads();  // B0: previous tile's agg2 reads of t16 done
    if (tid < 64) {
      rownode_s[pr][tid] = rn_next;
      rowgid_s[pr][tid] = rg_next;
    }
    // stage We1 into t16 bytes [0,16K): 256 rows x 64B, slot-swizzled
#pragma unroll
    for (int s = 0; s < 4; ++s) {
      int slot = tid + s * 256;
      int n = slot >> 2, cg = slot & 3;
      short8v w8 = *(const short8v*)((const short*)We1b + n * 32 + cg * 8);
      *(short8v*)(tb + n * 64 + ((cg * 16) ^ (((n >> 1) & 3) << 4))) = w8;
    }
    short8v a1 = a1_next;
    __syncthreads();  // B1: We1 staged, meta visible

    // e1 MFMA
    f32x4 acc1[16] = {};
#pragma unroll
    for (int nf = 0; nf < 16; ++nf) {
      int n = nf * 16 + l15;
      short8v b8 = *(const short8v*)(tb + n * 64 + ((grp * 16) ^ (((n >> 1) & 3) << 4)));
      acc1[nf] = __builtin_amdgcn_mfma_f32_16x16x32_bf16(a1, b8, acc1[nf], 0, 0, 0);
    }
#pragma unroll
    for (int nf = 0; nf < 16; ++nf) {
      float bv = be1[nf * 16 + l15];
#pragma unroll
      for (int i = 0; i < 4; ++i) {
        float v = acc1[nf][i] + bv;
        acc1[nf][i] = v > 0.f ? v : 0.f;
      }
    }
    __syncthreads();  // B2: We1 reads done -> overwrite with tile

#pragma unroll
    for (int i = 0; i < 4; ++i) {
      int row = base + grp * 4 + i;
      short8v lo, hi;
#pragma unroll
      for (int q = 0; q < 8; ++q) {
        lo[q] = f2bs(acc1[q][i]);
        hi[q] = f2bs(acc1[q + 8][i]);
      }
      *(short8v*)&t16[row * 264 + l15 * 16] = lo;
      *(short8v*)&t16[row * 264 + l15 * 16 + 8] = hi;
    }
    __syncthreads();  // B3: tile complete

    bool bnd = (lane == 63) || (rownode_s[pr][lane + 1] != rownode_s[pr][lane]);
    unsigned long long fmask = __ballot(bnd);
    unsigned long long amask = 0;
    {
      unsigned long long lsb = fmask & (~fmask + 1ull);
      if (offset[rownode_s[pr][0]] < p0) amask |= lsb;
      if (offset[rownode_s[pr][63] + 1] > p0 + 64) amask |= 1ull << 63;
    }

    short8v a2[8];
    const short* myrow = &t16[(base + l15) * 264];
#pragma unroll
    for (int s = 0; s < 8; ++s)
      a2[s] = *(const short8v*)(myrow + s * 32 + grp * 8);

    // ---- issue NEXT tile's prefetch (hidden under agg1 + e2)
    int rnN = 0, rgN = 0;
    short8v a1N;
    {
      const int tilen = blockIdx.x * 5 + ((t < 4) ? t + 1 : t);
      if (tid < 64) {
        rnN = pos2node[tilen * 64 + tid];
        rgN = node_graph[rnN];
      }
      int eN = pos2edge[tilen * 64 + base + l15];
      const float* erN = edge_feats + (size_t)eN * 32 + grp * 8;
      float4 aN = *(const float4*)erN;
      float4 bN = *(const float4*)(erN + 4);
      a1N[0] = f2bs(aN.x); a1N[1] = f2bs(aN.y);
      a1N[2] = f2bs(aN.z); a1N[3] = f2bs(aN.w);
      a1N[4] = f2bs(bN.x); a1N[5] = f2bs(bN.y);
      a1N[6] = f2bs(bN.z); a1N[7] = f2bs(bN.w);
    }

    // agg1: batched column sums, store/atomic split
    {
      int col = ((tid & 15) << 4) | (tid >> 4);  // pi(tid)
      float run = 0.f;
#pragma unroll
      for (int rb = 0; rb < 64; rb += 16) {
        float v[16];
#pragma unroll
        for (int i = 0; i < 16; ++i) v[i] = bs2f(t16[(rb + i) * 264 + tid]);
#pragma unroll
        for (int i = 0; i < 16; ++i) {
          run += v[i];
          int r = rb + i;
          if ((fmask >> r) & 1) {
            float* dst = &agg1f[(size_t)rownode_s[pr][r] * 256 + col];
            if ((amask >> r) & 1) atomicAdd(dst, run);
            else *dst = run;
            run = 0.f;
          }
        }
      }
    }
    __syncthreads();  // B4: agg1 + a2 reads done; tile dead

    // stage We2 chunk 0 -> buf0; refill wreg = chunk 1
#pragma unroll
    for (int s = 0; s < 4; ++s) {
      int n = n0w + s * 32;
      *(short8v*)(tb + n * 128 + ((cgw * 16) ^ ((n & 7) << 4))) = wreg[s];
    }
#pragma unroll
    for (int s = 0; s < 4; ++s)
      wreg[s] = *(const short8v*)((const short*)We2b +
                                  (size_t)(n0w + s * 32) * 256 + 64 + cgw * 8);
    __syncthreads();  // B5: chunk 0 visible

    // e2: 4 chunks, ping-pong; wreg refill rotates to next tile's chunk 0
    f32x4 acc2[8] = {};
#pragma unroll
    for (int c = 0; c < 4; ++c) {
      const int bufo = (c & 1) ? 16384 : 0;
      if (c < 3) {
        const int nbufo = ((c + 1) & 1) ? 16384 : 0;
#pragma unroll
        for (int s = 0; s < 4; ++s) {
          int n = n0w + s * 32;
          *(short8v*)(tb + nbufo + n * 128 + ((cgw * 16) ^ ((n & 7) << 4))) = wreg[s];
        }
        if (c < 2) {
#pragma unroll
          for (int s = 0; s < 4; ++s)
            wreg[s] = *(const short8v*)((const short*)We2b +
                                        (size_t)(n0w + s * 32) * 256 + (c + 2) * 64 + cgw * 8);
        } else {  // c == 2: preload chunk 0 for the NEXT tile
#pragma unroll
          for (int s = 0; s < 4; ++s)
            wreg[s] = *(const short8v*)((const short*)We2b +
                                        (size_t)(n0w + s * 32) * 256 + cgw * 8);
        }
      }
#pragma unroll
      for (int kki = 0; kki < 2; ++kki) {
#pragma unroll
        for (int nf = 0; nf < 8; ++nf) {
          int n = nf * 16 + l15;
          short8v b8 = *(const short8v*)(tb + bufo + n * 128 +
                                         (((kki * 64) + grp * 16) ^ ((n & 7) << 4)));
          acc2[nf] = __builtin_amdgcn_mfma_f32_16x16x32_bf16(a2[c * 2 + kki], b8,
                                                             acc2[nf], 0, 0, 0);
        }
      }
      if (c < 3) __syncthreads();  // B6,B7,B8
    }

    // e2 epilogue (VALU only)
    int gidr[4];
#pragma unroll
    for (int i = 0; i < 4; ++i) gidr[i] = rowgid_s[pr][base + grp * 4 + i];
#pragma unroll
    for (int nf = 0; nf < 8; ++nf) {
      int col = nf * 16 + l15;
      float bv = be2[col];
#pragma unroll
      for (int i = 0; i < 4; ++i) {
        float v = acc2[nf][i] + bv + g2e[gidr[i] * 128 + col];
        acc2[nf][i] = v > 0.f ? v : 0.f;
      }
    }
    __syncthreads();  // B9: chunk-3 MFMA reads done -> t16 free

    float* tf32 = (float*)t16;
#pragma unroll
    for (int i = 0; i < 4; ++i) {
      int row = base + grp * 4 + i;
      float4 lo = {acc2[0][i], acc2[1][i], acc2[2][i], acc2[3][i]};
      float4 hi = {acc2[4][i], acc2[5][i], acc2[6][i], acc2[7][i]};
      *(float4*)&tf32[row * 132 + l15 * 8] = lo;
      *(float4*)&tf32[row * 132 + l15 * 8 + 4] = hi;
    }
    __syncthreads();  // B10: f32 tile complete

    if (tid < 128) {
      int col = ((tid & 7) << 4) | (tid >> 3);  // pi2(tid)
      float run = 0.f;
#pragma unroll
      for (int rb = 0; rb < 64; rb += 16) {
        float v[16];
#pragma unroll
        for (int i = 0; i < 16; ++i) v[i] = tf32[(rb + i) * 132 + tid];
#pragma unroll
        for (int i = 0; i < 16; ++i) {
          run += v[i];
          int r = rb + i;
          if ((fmask >> r) & 1) {
            float* dst = &agg2f[(size_t)rownode_s[pr][r] * 128 + col];
            if ((amask >> r) & 1) atomicAdd(dst, run);
            else *dst = run;
            run = 0.f;
          }
        }
      }
    }
    // register handoff to next tile
    rn_next = rnN;
    rg_next = rgN;
    a1_next = a1N;
  }
}

// ---------------------------------------------------------------------------
// FUSED node pipeline (v2, unchanged): deep register prefetch, fused gsum.
__global__ __launch_bounds__(256, 2) void k_node(
    const bf16* __restrict__ nfb, const float* __restrict__ agg1f,
    const float* __restrict__ agg2f, const int* __restrict__ offset,
    const bf16* __restrict__ Wn1b, const bf16* __restrict__ Wn2b,
    const float* __restrict__ bn1, const float* __restrict__ bn2,
    const float* __restrict__ g2n, const int* __restrict__ node_graph,
    float* __restrict__ node_sum, float* __restrict__ edge_sum) {
  __shared__ __align__(16) char smem_w[32768];
  __shared__ __align__(16) short t16[64 * 264];
  __shared__ int rowgid_s[64];
  const int tid = threadIdx.x;
  const int wave = tid >> 6, lane = tid & 63;
  const int l15 = lane & 15, grp = lane >> 4;
  const int r0 = blockIdx.x * 64;
  const int base = wave * 16;
  const int n0w = tid >> 3, cgw = tid & 7;

  if (tid < 64) {
    int n = r0 + tid;
    rowgid_s[tid] = node_graph[n < N_NODES ? n : N_NODES - 1];
  }
  long arow = r0 + base + l15;
  if (arow >= N_NODES) arow = N_NODES - 1;
  int dg = offset[arow + 1] - offset[arow];
  const float inv = 1.f / (float)(dg > 1 ? dg : 1);

  short8v a1all[10];
#pragma unroll
  for (int kki = 0; kki < 2; ++kki)
    a1all[kki] = *(const short8v*)((const short*)nfb + (size_t)arow * 64 + kki * 32 + grp * 8);
#pragma unroll
  for (int c = 1; c < 5; ++c) {
#pragma unroll
    for (int kki = 0; kki < 2; ++kki) {
      int k = c * 64 + kki * 32 + grp * 8;
      const float* p = agg1f + (size_t)arow * 256 + (k - 64);
      float4 f0 = *(const float4*)p;
      float4 f1 = *(const float4*)(p + 4);
      short8v t;
      t[0] = f2bs(f0.x * inv); t[1] = f2bs(f0.y * inv);
      t[2] = f2bs(f0.z * inv); t[3] = f2bs(f0.w * inv);
      t[4] = f2bs(f1.x * inv); t[5] = f2bs(f1.y * inv);
      t[6] = f2bs(f1.z * inv); t[7] = f2bs(f1.w * inv);
      a1all[c * 2 + kki] = t;
    }
  }

  short8v w1x[8], w1y[8];
#pragma unroll
  for (int s = 0; s < 8; ++s)
    w1x[s] = *(const short8v*)((const short*)Wn1b + (size_t)(n0w + s * 32) * 320 + cgw * 8);
#pragma unroll
  for (int s = 0; s < 8; ++s)
    w1y[s] = *(const short8v*)((const short*)Wn1b + (size_t)(n0w + s * 32) * 320 + 64 + cgw * 8);
  f32x4 acc1[16] = {};
#pragma unroll
  for (int c = 0; c < 5; ++c) {
    if (c > 0) __syncthreads();
#pragma unroll
    for (int s = 0; s < 8; ++s) {
      int n = n0w + s * 32;
      *(short8v*)(smem_w + n * 128 + ((cgw * 16) ^ ((n & 7) << 4))) =
          (c & 1) ? w1y[s] : w1x[s];
    }
    if (c + 2 < 5) {
#pragma unroll
      for (int s = 0; s < 8; ++s) {
        short8v t = *(const short8v*)((const short*)Wn1b +
                                      (size_t)(n0w + s * 32) * 320 + (c + 2) * 64 + cgw * 8);
        if (c & 1) w1y[s] = t;
        else w1x[s] = t;
      }
    }
    __syncthreads();
#pragma unroll
    for (int kki = 0; kki < 2; ++kki) {
#pragma unroll
      for (int nf = 0; nf < 16; ++nf) {
        int wrow = nf * 16 + l15;
        short8v b8 = *(const short8v*)(smem_w + wrow * 128 +
                                       (((kki * 64) + grp * 16) ^ ((wrow & 7) << 4)));
        acc1[nf] = __builtin_amdgcn_mfma_f32_16x16x32_bf16(a1all[c * 2 + kki], b8,
                                                           acc1[nf], 0, 0, 0);
      }
    }
  }

#pragma unroll
  for (int nf = 0; nf < 16; ++nf) {
    float bv = bn1[nf * 16 + l15];
#pragma unroll
    for (int i = 0; i < 4; ++i) {
      float v = acc1[nf][i] + bv;
      acc1[nf][i] = v > 0.f ? v : 0.f;
    }
  }
#pragma unroll
  for (int i = 0; i < 4; ++i) {
    int row = base + grp * 4 + i;
    short8v lo, hi;
#pragma unroll
    for (int q = 0; q < 8; ++q) {
      lo[q] = f2bs(acc1[q][i]);
      hi[q] = f2bs(acc1[q + 8][i]);
    }
    *(short8v*)&t16[row * 264 + l15 * 16] = lo;
    *(short8v*)&t16[row * 264 + l15 * 16 + 8] = hi;
  }
  short8v a2all[12];
  const short* myrow = &t16[(base + l15) * 264];
#pragma unroll
  for (int s = 0; s < 8; ++s)
    a2all[s] = *(const short8v*)(myrow + s * 32 + grp * 8);
#pragma unroll
  for (int c = 4; c < 6; ++c) {
#pragma unroll
    for (int kki = 0; kki < 2; ++kki) {
      int k = (c - 4) * 64 + kki * 32 + grp * 8;
      const float* p = agg2f + (size_t)arow * 128 + k;
      float4 f0 = *(const float4*)p;
      float4 f1 = *(const float4*)(p + 4);
      short8v t;
      t[0] = f2bs(f0.x * inv); t[1] = f2bs(f0.y * inv);
      t[2] = f2bs(f0.z * inv); t[3] = f2bs(f0.w * inv);
      t[4] = f2bs(f1.x * inv); t[5] = f2bs(f1.y * inv);
      t[6] = f2bs(f1.z * inv); t[7] = f2bs(f1.w * inv);
      a2all[c * 2 + kki] = t;
    }
  }
  short8v w2r[24];
#pragma unroll
  for (int c = 0; c < 6; ++c)
#pragma unroll
    for (int s = 0; s < 4; ++s)
      w2r[c * 4 + s] = *(const short8v*)((const short*)Wn2b +
                                         (size_t)(n0w + s * 32) * 384 + c * 64 + cgw * 8);

  f32x4 acc2[8] = {};
#pragma unroll
  for (int c = 0; c < 6; ++c) {
    __syncthreads();
#pragma unroll
    for (int s = 0; s < 4; ++s) {
      int n = n0w + s * 32;
      *(short8v*)(smem_w + n * 128 + ((cgw * 16) ^ ((n & 7) << 4))) = w2r[c * 4 + s];
    }
    __syncthreads();
#pragma unroll
    for (int kki = 0; kki < 2; ++kki) {
#pragma unroll
      for (int nf = 0; nf < 8; ++nf) {
        int wrow = nf * 16 + l15;
        short8v b8 = *(const short8v*)(smem_w + wrow * 128 +
                                       (((kki * 64) + grp * 16) ^ ((wrow & 7) << 4)));
        acc2[nf] = __builtin_amdgcn_mfma_f32_16x16x32_bf16(a2all[c * 2 + kki], b8,
                                                           acc2[nf], 0, 0, 0);
      }
    }
  }

  float* tf32 = (float*)t16;
  int gidr[4];
#pragma unroll
  for (int i = 0; i < 4; ++i) gidr[i] = rowgid_s[base + grp * 4 + i];
#pragma unroll
  for (int nf = 0; nf < 8; ++nf) {
    int col = nf * 16 + l15;
    float bv = bn2[col];
#pragma unroll
    for (int i = 0; i < 4; ++i) {
      float v = acc2[nf][i] + bv + g2n[gidr[i] * 128 + col];
      acc2[nf][i] = v > 0.f ? v : 0.f;
    }
  }
#pragma unroll
  for (int i = 0; i < 4; ++i) {
    int row = base + grp * 4 + i;
    float4 lo = {acc2[0][i], acc2[1][i], acc2[2][i], acc2[3][i]};
    float4 hi = {acc2[4][i], acc2[5][i], acc2[6][i], acc2[7][i]};
    *(float4*)&tf32[row * 132 + l15 * 8] = lo;
    *(float4*)&tf32[row * 132 + l15 * 8 + 4] = hi;
  }
  __syncthreads();

  bool gb = (lane == 63) || (rowgid_s[lane + 1] != rowgid_s[lane]);
  unsigned long long gmask = __ballot(gb);
  if (tid < 128) {
    int col = ((tid & 7) << 4) | (tid >> 3);  // pi2(tid)
    float rn_ = 0.f, re_ = 0.f;
#pragma unroll
    for (int rb = 0; rb < 64; rb += 16) {
      float vn[16], ve[16];
#pragma unroll
      for (int i = 0; i < 16; ++i) {
        int r = rb + i;
        long row = (long)r0 + r;
        bool ok = row < N_NODES;
        vn[i] = ok ? tf32[r * 132 + tid] : 0.f;
        ve[i] = ok ? agg2f[(size_t)row * 128 + col] : 0.f;
      }
#pragma unroll
      for (int i = 0; i < 16; ++i) {
        int r = rb + i;
        rn_ += vn[i];
        re_ += ve[i];
        if ((gmask >> r) & 1) {
          int g = rowgid_s[r];
          atomicAdd(&node_sum[g * 128 + col], rn_);
          atomicAdd(&edge_sum[g * 128 + col], re_);
          rn_ = 0.f;
          re_ = 0.f;
        }
      }
    }
  }
}

// ---------------------------------------------------------------------------
// K7: out = node_avg @ Wgn.T + edge_avg @ Wge.T + gg   [16,128]
__global__ __launch_bounds__(128) void k_final(
    const float* __restrict__ node_sum, const float* __restrict__ edge_sum,
    const int* __restrict__ node_cnt_g, const int* __restrict__ edge_cnt_g,
    const float* __restrict__ Wgn, const float* __restrict__ Wge,
    const float* __restrict__ gg, float* __restrict__ out) {
  __shared__ float navg[128], eavg[128];
  const int g = blockIdx.x, c = threadIdx.x;
  int nc = node_cnt_g[g];
  nc = nc > 1 ? nc : 1;
  int ec = edge_cnt_g[g];
  ec = ec > 1 ? ec : 1;
  navg[c] = node_sum[g * 128 + c] / (float)nc;
  eavg[c] = edge_sum[g * 128 + c] / (float)ec;
  __syncthreads();
  float acc = gg[g * 128 + c];
#pragma unroll 4
  for (int k = 0; k < 128; ++k)
    acc += navg[k] * Wgn[c * 128 + k] + eavg[k] * Wge[c * 128 + k];
  out[g * 128 + c] = acc;
}

// ---------------------------------------------------------------------------
extern "C" void kernel_launch(void* const* d_in, const int* in_sizes, int n_in,
                              void* d_out, int out_size, void* d_ws, size_t ws_size,
                              hipStream_t stream) {
  const float* node_feats = (const float*)d_in[0];
  const float* edge_feats = (const float*)d_in[1];
  const float* globals_ = (const float*)d_in[2];
  const float* We1 = (const float*)d_in[3];
  const float* be1 = (const float*)d_in[4];
  const float* Wn1 = (const float*)d_in[5];
  const float* Win1 = (const float*)d_in[6];
  const float* bn1 = (const float*)d_in[7];
  const float* We2 = (const float*)d_in[8];
  const float* Wg2 = (const float*)d_in[9];
  const float* be2 = (const float*)d_in[10];
  const float* Wn2 = (const float*)d_in[11];
  const float* Win2 = (const float*)d_in[12];
  const float* Wng2 = (const float*)d_in[13];
  const float* bn2 = (const float*)d_in[14];
  const float* Wgn = (const float*)d_in[15];
  const float* Wge = (const float*)d_in[16];
  const float* Wgg = (const float*)d_in[17];
  const float* bg = (const float*)d_in[18];
  const int* receivers = (const int*)d_in[19];
  const int* node_graph = (const int*)d_in[20];
  float* out = (float*)d_out;

  char* ws = (char*)d_ws;
  size_t off = 0;
  auto alloc = [&](size_t bytes) {
    size_t o = off;
    off += (bytes + 255) & ~(size_t)255;
    return o;
  };
  const int NP = 20032;  // N_NODES padded to 64
  // --- zero region (accumulators) ---
  int* cnt_node = (int*)(ws + alloc((size_t)N_NODES * 4));
  int* node_cnt_g = (int*)(ws + alloc(NG * 4));
  int* edge_cnt_g = (int*)(ws + alloc(NG * 4));
  float* node_sum = (float*)(ws + alloc(NG * 128 * 4));
  float* edge_sum = (float*)(ws + alloc(NG * 128 * 4));
  float* agg1f = (float*)(ws + alloc((size_t)N_NODES * 256 * 4));
  float* agg2f = (float*)(ws + alloc((size_t)N_NODES * 128 * 4));
  size_t zero_bytes = off;
  // --- rewritten every call ---
  int* offset = (int*)(ws + alloc((size_t)(N_NODES + 1) * 4));
  int* cursor = (int*)(ws + alloc((size_t)N_NODES * 4));
  int* pos2edge = (int*)(ws + alloc((size_t)N_EDGES * 4));
  int* pos2node = (int*)(ws + alloc((size_t)N_EDGES * 4));
  float* g2e = (float*)(ws + alloc(NG * 128 * 4));
  float* g2n = (float*)(ws + alloc(NG * 128 * 4));
  float* gg = (float*)(ws + alloc(NG * 128 * 4));
  bf16* Wb_e1 = (bf16*)(ws + alloc(8192 * 2));
  bf16* Wb_n1 = (bf16*)(ws + alloc(81920 * 2));
  bf16* Wb_e2 = (bf16*)(ws + alloc(32768 * 2));
  bf16* Wb_n2 = (bf16*)(ws + alloc(49152 * 2));
  bf16* nfb = (bf16*)(ws + alloc((size_t)NP * 64 * 2));
  (void)ws_size;

  hipMemsetAsync(d_ws, 0, zero_bytes, stream);
  k_prep<<<1946, 256, 0, stream>>>(globals_, Wg2, Wng2, Wgg, bg, g2e, g2n, gg,
                                   We1, Wn1, Win1, We2, Wn2, Win2, Wb_e1,
                                   Wb_n1, Wb_e2, Wb_n2, node_feats, nfb);
  k_counts<<<(N_EDGES + N_NODES + 255) / 256, 256, 0, stream>>>(
      receivers, node_graph, cnt_node, node_cnt_g, edge_cnt_g);
  k_scan<<<1, 256, 0, stream>>>(cnt_node, offset, cursor);
  k_scatter<<<(N_EDGES + 255) / 256, 256, 0, stream>>>(receivers, offset,
                                                       cursor, pos2edge,
                                                       pos2node);
  k_edge<<<1000, 256, 0, stream>>>(edge_feats, Wb_e1, Wb_e2, be1, be2,
                                   g2e, pos2edge, pos2node, node_graph,
                                   offset, agg1f, agg2f);
  k_node<<<NP / 64, 256, 0, stream>>>(nfb, agg1f, agg2f, offset, Wb_n1, Wb_n2,
                                      bn1, bn2, g2n, node_graph, node_sum,
                                      edge_sum);
  k_final<<<NG, 128, 0, stream>>>(node_sum, edge_sum, node_cnt_g, edge_cnt_g,
                                  Wgn, Wge, gg, out);
}

// Round 17
// 195.518 us; speedup vs baseline: 1.2242x; 1.2242x over previous
//
#include <hip/hip_runtime.h>
#include <hip/hip_bf16.h>

#define N_NODES 20000
#define N_EDGES 320000
#define NG 16

using bf16 = __hip_bfloat16;
typedef __attribute__((ext_vector_type(8))) short short8v;
typedef __attribute__((ext_vector_type(4))) short short4v;
typedef __attribute__((ext_vector_type(4))) float f32x4;

static __device__ __forceinline__ short f2bs(float f) {
  bf16 h = __float2bfloat16(f);
  union { bf16 b; short s; } u;
  u.b = h;
  return u.s;
}
static __device__ __forceinline__ float bs2f(short s) {
  union { short s; bf16 b; } u;
  u.s = s;
  return __bfloat162float(u.b);
}

// ---------------------------------------------------------------------------
// K_prep: globals matmuls, weight bf16 cvt (pi for We2b; pi on first 256
// k-cols of Wb_n2), node_feats -> nfb.
__global__ __launch_bounds__(256) void k_prep(
    const float* __restrict__ globals_, const float* __restrict__ Wg2,
    const float* __restrict__ Wng2, const float* __restrict__ Wgg,
    const float* __restrict__ bg, float* __restrict__ g2e,
    float* __restrict__ g2n, float* __restrict__ gg,
    const float* __restrict__ We1, const float* __restrict__ Wn1,
    const float* __restrict__ Win1, const float* __restrict__ We2,
    const float* __restrict__ Wn2, const float* __restrict__ Win2,
    bf16* __restrict__ Wb_e1, bf16* __restrict__ Wb_n1,
    bf16* __restrict__ Wb_e2, bf16* __restrict__ Wb_n2,
    const float* __restrict__ nf, bf16* __restrict__ nfb) {
  int idx = blockIdx.x * 256 + threadIdx.x;
  if (idx < 6144) {
    int arr = idx >> 11;
    int rem = idx & 2047;
    int g = rem >> 7, c = rem & 127;
    const float* W = arr == 0 ? Wg2 : (arr == 1 ? Wng2 : Wgg);
    float acc = (arr == 2) ? bg[c] : 0.f;
#pragma unroll
    for (int k = 0; k < 16; ++k) acc += globals_[g * 16 + k] * W[c * 16 + k];
    float* o = arr == 0 ? g2e : (arr == 1 ? g2n : gg);
    o[rem] = acc;
    return;
  }
  idx -= 6144;
  if (idx < 172032) {
    int i = idx;
    float v;
    bf16* dst;
    int di;
    if (i < 8192) {
      v = We1[i]; dst = Wb_e1; di = i;
    } else if (i < 90112) {
      int j = i - 8192, r = j / 320, c = j % 320;
      v = c < 64 ? Wn1[r * 64 + c] : Win1[r * 256 + (c - 64)];
      dst = Wb_n1; di = j;
    } else if (i < 122880) {
      int j = i - 90112;
      int n = j >> 8, p = j & 255;
      int k = ((p & 15) << 4) | (p >> 4);  // pi (self-inverse 16x16 transpose)
      v = We2[n * 256 + k];
      dst = Wb_e2; di = j;
    } else {
      int j = i - 122880, r = j / 384, c = j % 384;
      if (c < 256) {
        int k = ((c & 15) << 4) | (c >> 4);  // pi on n1 k-axis
        v = Wn2[r * 256 + k];
      } else {
        v = Win2[r * 128 + (c - 256)];
      }
      dst = Wb_n2; di = j;
    }
    dst[di] = __float2bfloat16(v);
    return;
  }
  idx -= 172032;
  if (idx < 320000) {
    int n = idx >> 4, q = idx & 15;
    float4 v = *(const float4*)(nf + (size_t)n * 64 + q * 4);
    short4v o = {f2bs(v.x), f2bs(v.y), f2bs(v.z), f2bs(v.w)};
    *(short4v*)((short*)nfb + (size_t)n * 64 + q * 4) = o;
  }
}

// ---------------------------------------------------------------------------
// K1: counts.
__global__ __launch_bounds__(256) void k_counts(
    const int* __restrict__ recv, const int* __restrict__ node_graph,
    int* __restrict__ cnt_node, int* __restrict__ node_cnt_g,
    int* __restrict__ edge_cnt_g) {
  __shared__ int le[NG], ln[NG];
  int tid = threadIdx.x;
  if (tid < NG) { le[tid] = 0; ln[tid] = 0; }
  __syncthreads();
  int idx = blockIdx.x * 256 + tid;
  if (idx < N_EDGES) {
    int r = recv[idx];
    atomicAdd(&cnt_node[r], 1);
    atomicAdd(&le[node_graph[r]], 1);
  } else if (idx < N_EDGES + N_NODES) {
    int n = idx - N_EDGES;
    atomicAdd(&ln[node_graph[n]], 1);
  }
  __syncthreads();
  if (tid < NG && le[tid]) atomicAdd(&edge_cnt_g[tid], le[tid]);
  if (tid >= NG && tid < 2 * NG && ln[tid - NG]) atomicAdd(&node_cnt_g[tid - NG], ln[tid - NG]);
}

// ---------------------------------------------------------------------------
// K1b: exclusive prefix sum (shuffle-based, 1024 elems/iter).
__global__ __launch_bounds__(256) void k_scan(const int* __restrict__ cnt,
                                              int* __restrict__ offset,
                                              int* __restrict__ cursor) {
  __shared__ int wsum[4];
  __shared__ int carry_s;
  int tid = threadIdx.x, lane = tid & 63, wv = tid >> 6;
  if (tid == 0) carry_s = 0;
  __syncthreads();
  for (int base = 0; base < N_NODES; base += 1024) {
    int idx = base + tid * 4;
    int v[4];
    int s = 0;
#pragma unroll
    for (int i = 0; i < 4; ++i) {
      v[i] = (idx + i < N_NODES) ? cnt[idx + i] : 0;
      s += v[i];
    }
    int ps = s;
#pragma unroll
    for (int d = 1; d < 64; d <<= 1) {
      int t = __shfl_up(ps, d, 64);
      if (lane >= d) ps += t;
    }
    if (lane == 63) wsum[wv] = ps;
    __syncthreads();
    int wbase = carry_s;
    for (int w2 = 0; w2 < wv; ++w2) wbase += wsum[w2];
    int run = wbase + ps - s;
#pragma unroll
    for (int i = 0; i < 4; ++i) {
      if (idx + i < N_NODES) {
        offset[idx + i] = run;
        cursor[idx + i] = 0;
      }
      run += v[i];
    }
    __syncthreads();
    if (tid == 0) carry_s += wsum[0] + wsum[1] + wsum[2] + wsum[3];
    __syncthreads();
  }
  if (tid == 0) offset[N_NODES] = carry_s;
}

// ---------------------------------------------------------------------------
// K1c: scatter edges into CSR positions.
__global__ __launch_bounds__(256) void k_scatter(
    const int* __restrict__ recv, const int* __restrict__ offset,
    int* __restrict__ cursor, int* __restrict__ pos2edge,
    int* __restrict__ pos2node) {
  int e = blockIdx.x * 256 + threadIdx.x;
  if (e >= N_EDGES) return;
  int n = recv[e];
  int slot = atomicAdd(&cursor[n], 1);
  int pos = offset[n] + slot;
  pos2edge[pos] = e;
  pos2node[pos] = n;
}

// ---------------------------------------------------------------------------
// FUSED edge pipeline (v9, the measured optimum): LDS-alias diet +
// low-register streaming We2 (wreg[4] only).  t16 bytes multiplexed:
// We1 stage / e1 tile / We2 ping-pong / f32 tile.  34.3 KB -> 4 blocks/CU,
// 60 VGPR, no spill.  [r14/r16 lesson: deeper register pipelines spill at
// the 128-VGPR cap; 3-block variants lose more to occupancy than they gain.]
__global__ __launch_bounds__(256, 4) void k_edge(
    const float* __restrict__ edge_feats, const bf16* __restrict__ We1b,
    const bf16* __restrict__ We2b, const float* __restrict__ be1,
    const float* __restrict__ be2, const float* __restrict__ g2e,
    const int* __restrict__ pos2edge, const int* __restrict__ pos2node,
    const int* __restrict__ node_graph, const int* __restrict__ offset,
    float* __restrict__ agg1f, float* __restrict__ agg2f) {
  __shared__ __align__(16) short t16[64 * 264];  // 33792B multiplexed
  __shared__ int rownode_s[64];
  __shared__ int rowgid_s[64];
  char* tb = (char*)t16;
  const int tid = threadIdx.x;
  const int wave = tid >> 6, lane = tid & 63;
  const int l15 = lane & 15, grp = lane >> 4;
  const int p0 = blockIdx.x * 64;
  const int base = wave * 16;

  if (tid < 64) {
    int rn = pos2node[p0 + tid];
    rownode_s[tid] = rn;
    rowgid_s[tid] = node_graph[rn];
  }
  const int n0w = tid >> 3, cgw = tid & 7;
  // We2 chunk-0 preload only (16 VGPR; lands during e1 phase)
  short8v wreg[4];
#pragma unroll
  for (int s = 0; s < 4; ++s)
    wreg[s] = *(const short8v*)((const short*)We2b + (size_t)(n0w + s * 32) * 256 + cgw * 8);
  // stage We1 into t16 bytes [0,16K): 256 rows x 64B, slot-swizzled
#pragma unroll
  for (int s = 0; s < 4; ++s) {
    int slot = tid + s * 256;
    int n = slot >> 2, cg = slot & 3;
    short8v w8 = *(const short8v*)((const short*)We1b + n * 32 + cg * 8);
    *(short8v*)(tb + n * 64 + ((cg * 16) ^ (((n >> 1) & 3) << 4))) = w8;
  }
  int e = pos2edge[p0 + base + l15];
  const float* efrow = edge_feats + (size_t)e * 32 + grp * 8;
  float4 af0 = *(const float4*)(efrow);
  float4 af1 = *(const float4*)(efrow + 4);
  short8v a1;
  a1[0] = f2bs(af0.x); a1[1] = f2bs(af0.y); a1[2] = f2bs(af0.z); a1[3] = f2bs(af0.w);
  a1[4] = f2bs(af1.x); a1[5] = f2bs(af1.y); a1[6] = f2bs(af1.z); a1[7] = f2bs(af1.w);
  __syncthreads();  // #1: We1 staged, meta ready

  // e1 MFMA (reads We1 from t16 bytes)
  f32x4 acc1[16] = {};
#pragma unroll
  for (int nf = 0; nf < 16; ++nf) {
    int n = nf * 16 + l15;
    short8v b8 = *(const short8v*)(tb + n * 64 + ((grp * 16) ^ (((n >> 1) & 3) << 4)));
    acc1[nf] = __builtin_amdgcn_mfma_f32_16x16x32_bf16(a1, b8, acc1[nf], 0, 0, 0);
  }
#pragma unroll
  for (int nf = 0; nf < 16; ++nf) {
    float bv = be1[nf * 16 + l15];
#pragma unroll
    for (int i = 0; i < 4; ++i) {
      float v = acc1[nf][i] + bv;
      acc1[nf][i] = v > 0.f ? v : 0.f;
    }
  }
  __syncthreads();  // #2: all We1 reads done -> safe to overwrite with tile

  // pi-layout tile write
#pragma unroll
  for (int i = 0; i < 4; ++i) {
    int row = base + grp * 4 + i;
    short8v lo, hi;
#pragma unroll
    for (int q = 0; q < 8; ++q) {
      lo[q] = f2bs(acc1[q][i]);
      hi[q] = f2bs(acc1[q + 8][i]);
    }
    *(short8v*)&t16[row * 264 + l15 * 16] = lo;
    *(short8v*)&t16[row * 264 + l15 * 16 + 8] = hi;
  }
  __syncthreads();  // #3: tile complete

  bool bnd = (lane == 63) || (rownode_s[lane + 1] != rownode_s[lane]);
  unsigned long long fmask = __ballot(bnd);
  unsigned long long amask = 0;
  {
    unsigned long long lsb = fmask & (~fmask + 1ull);
    if (offset[rownode_s[0]] < p0) amask |= lsb;
    if (offset[rownode_s[63] + 1] > p0 + 64) amask |= 1ull << 63;
  }

  short8v a2[8];
  const short* myrow = &t16[(base + l15) * 264];
#pragma unroll
  for (int s = 0; s < 8; ++s)
    a2[s] = *(const short8v*)(myrow + s * 32 + grp * 8);

  // agg1: batched column sums, store/atomic split
  {
    int col = ((tid & 15) << 4) | (tid >> 4);  // pi(tid)
    float run = 0.f;
#pragma unroll
    for (int rb = 0; rb < 64; rb += 16) {
      float v[16];
#pragma unroll
      for (int i = 0; i < 16; ++i) v[i] = bs2f(t16[(rb + i) * 264 + tid]);
#pragma unroll
      for (int i = 0; i < 16; ++i) {
        run += v[i];
        int r = rb + i;
        if ((fmask >> r) & 1) {
          float* dst = &agg1f[(size_t)rownode_s[r] * 256 + col];
          if ((amask >> r) & 1) atomicAdd(dst, run);
          else *dst = run;
          run = 0.f;
        }
      }
    }
  }
  __syncthreads();  // #4: agg1 + a2 reads done; tile dead

  // stage We2 chunk 0 -> buf0 = t16 bytes [0,16K); refill wreg = chunk 1
#pragma unroll
  for (int s = 0; s < 4; ++s) {
    int n = n0w + s * 32;
    *(short8v*)(tb + n * 128 + ((cgw * 16) ^ ((n & 7) << 4))) = wreg[s];
  }
#pragma unroll
  for (int s = 0; s < 4; ++s)
    wreg[s] = *(const short8v*)((const short*)We2b + (size_t)(n0w + s * 32) * 256 + 64 + cgw * 8);
  __syncthreads();  // #5: chunk 0 visible

  // e2: 4 chunks, ping-pong buffers inside t16, depth-1.5 streaming
  f32x4 acc2[8] = {};
#pragma unroll
  for (int c = 0; c < 4; ++c) {
    const int bufo = (c & 1) ? 16384 : 0;
    if (c < 3) {
      // stage chunk c+1 into the other buffer (overlaps this chunk's MFMA)
      const int nbufo = ((c + 1) & 1) ? 16384 : 0;
#pragma unroll
      for (int s = 0; s < 4; ++s) {
        int n = n0w + s * 32;
        *(short8v*)(tb + nbufo + n * 128 + ((cgw * 16) ^ ((n & 7) << 4))) = wreg[s];
      }
      if (c < 2) {
        // refill wreg with chunk c+2 (consumed next iteration)
#pragma unroll
        for (int s = 0; s < 4; ++s)
          wreg[s] = *(const short8v*)((const short*)We2b +
                                      (size_t)(n0w + s * 32) * 256 + (c + 2) * 64 + cgw * 8);
      }
    }
#pragma unroll
    for (int kki = 0; kki < 2; ++kki) {
#pragma unroll
      for (int nf = 0; nf < 8; ++nf) {
        int n = nf * 16 + l15;
        short8v b8 = *(const short8v*)(tb + bufo + n * 128 +
                                       (((kki * 64) + grp * 16) ^ ((n & 7) << 4)));
        acc2[nf] = __builtin_amdgcn_mfma_f32_16x16x32_bf16(a2[c * 2 + kki], b8,
                                                           acc2[nf], 0, 0, 0);
      }
    }
    if (c < 3) __syncthreads();  // #6,#7,#8
  }

  // e2 epilogue: bias + g2e + relu (VALU only)
  int gidr[4];
#pragma unroll
  for (int i = 0; i < 4; ++i) gidr[i] = rowgid_s[base + grp * 4 + i];
#pragma unroll
  for (int nf = 0; nf < 8; ++nf) {
    int col = nf * 16 + l15;
    float bv = be2[col];
#pragma unroll
    for (int i = 0; i < 4; ++i) {
      float v = acc2[nf][i] + bv + g2e[gidr[i] * 128 + col];
      acc2[nf][i] = v > 0.f ? v : 0.f;
    }
  }
  __syncthreads();  // #9: chunk-3 MFMA reads done -> t16 bytes free

  float* tf32 = (float*)t16;
#pragma unroll
  for (int i = 0; i < 4; ++i) {
    int row = base + grp * 4 + i;
    float4 lo = {acc2[0][i], acc2[1][i], acc2[2][i], acc2[3][i]};
    float4 hi = {acc2[4][i], acc2[5][i], acc2[6][i], acc2[7][i]};
    *(float4*)&tf32[row * 132 + l15 * 8] = lo;
    *(float4*)&tf32[row * 132 + l15 * 8 + 4] = hi;
  }
  __syncthreads();  // #10: f32 tile complete

  if (tid < 128) {
    int col = ((tid & 7) << 4) | (tid >> 3);  // pi2(tid)
    float run = 0.f;
#pragma unroll
    for (int rb = 0; rb < 64; rb += 16) {
      float v[16];
#pragma unroll
      for (int i = 0; i < 16; ++i) v[i] = tf32[(rb + i) * 132 + tid];
#pragma unroll
      for (int i = 0; i < 16; ++i) {
        run += v[i];
        int r = rb + i;
        if ((fmask >> r) & 1) {
          float* dst = &agg2f[(size_t)rownode_s[r] * 128 + col];
          if ((amask >> r) & 1) atomicAdd(dst, run);
          else *dst = run;
          run = 0.f;
        }
      }
    }
  }
}

// ---------------------------------------------------------------------------
// FUSED node pipeline (v2, unchanged): deep register prefetch, fused gsum.
__global__ __launch_bounds__(256, 2) void k_node(
    const bf16* __restrict__ nfb, const float* __restrict__ agg1f,
    const float* __restrict__ agg2f, const int* __restrict__ offset,
    const bf16* __restrict__ Wn1b, const bf16* __restrict__ Wn2b,
    const float* __restrict__ bn1, const float* __restrict__ bn2,
    const float* __restrict__ g2n, const int* __restrict__ node_graph,
    float* __restrict__ node_sum, float* __restrict__ edge_sum) {
  __shared__ __align__(16) char smem_w[32768];
  __shared__ __align__(16) short t16[64 * 264];
  __shared__ int rowgid_s[64];
  const int tid = threadIdx.x;
  const int wave = tid >> 6, lane = tid & 63;
  const int l15 = lane & 15, grp = lane >> 4;
  const int r0 = blockIdx.x * 64;
  const int base = wave * 16;
  const int n0w = tid >> 3, cgw = tid & 7;

  if (tid < 64) {
    int n = r0 + tid;
    rowgid_s[tid] = node_graph[n < N_NODES ? n : N_NODES - 1];
  }
  long arow = r0 + base + l15;
  if (arow >= N_NODES) arow = N_NODES - 1;
  int dg = offset[arow + 1] - offset[arow];
  const float inv = 1.f / (float)(dg > 1 ? dg : 1);

  short8v a1all[10];
#pragma unroll
  for (int kki = 0; kki < 2; ++kki)
    a1all[kki] = *(const short8v*)((const short*)nfb + (size_t)arow * 64 + kki * 32 + grp * 8);
#pragma unroll
  for (int c = 1; c < 5; ++c) {
#pragma unroll
    for (int kki = 0; kki < 2; ++kki) {
      int k = c * 64 + kki * 32 + grp * 8;
      const float* p = agg1f + (size_t)arow * 256 + (k - 64);
      float4 f0 = *(const float4*)p;
      float4 f1 = *(const float4*)(p + 4);
      short8v t;
      t[0] = f2bs(f0.x * inv); t[1] = f2bs(f0.y * inv);
      t[2] = f2bs(f0.z * inv); t[3] = f2bs(f0.w * inv);
      t[4] = f2bs(f1.x * inv); t[5] = f2bs(f1.y * inv);
      t[6] = f2bs(f1.z * inv); t[7] = f2bs(f1.w * inv);
      a1all[c * 2 + kki] = t;
    }
  }

  short8v w1x[8], w1y[8];
#pragma unroll
  for (int s = 0; s < 8; ++s)
    w1x[s] = *(const short8v*)((const short*)Wn1b + (size_t)(n0w + s * 32) * 320 + cgw * 8);
#pragma unroll
  for (int s = 0; s < 8; ++s)
    w1y[s] = *(const short8v*)((const short*)Wn1b + (size_t)(n0w + s * 32) * 320 + 64 + cgw * 8);
  f32x4 acc1[16] = {};
#pragma unroll
  for (int c = 0; c < 5; ++c) {
    if (c > 0) __syncthreads();
#pragma unroll
    for (int s = 0; s < 8; ++s) {
      int n = n0w + s * 32;
      *(short8v*)(smem_w + n * 128 + ((cgw * 16) ^ ((n & 7) << 4))) =
          (c & 1) ? w1y[s] : w1x[s];
    }
    if (c + 2 < 5) {
#pragma unroll
      for (int s = 0; s < 8; ++s) {
        short8v t = *(const short8v*)((const short*)Wn1b +
                                      (size_t)(n0w + s * 32) * 320 + (c + 2) * 64 + cgw * 8);
        if (c & 1) w1y[s] = t;
        else w1x[s] = t;
      }
    }
    __syncthreads();
#pragma unroll
    for (int kki = 0; kki < 2; ++kki) {
#pragma unroll
      for (int nf = 0; nf < 16; ++nf) {
        int wrow = nf * 16 + l15;
        short8v b8 = *(const short8v*)(smem_w + wrow * 128 +
                                       (((kki * 64) + grp * 16) ^ ((wrow & 7) << 4)));
        acc1[nf] = __builtin_amdgcn_mfma_f32_16x16x32_bf16(a1all[c * 2 + kki], b8,
                                                           acc1[nf], 0, 0, 0);
      }
    }
  }

#pragma unroll
  for (int nf = 0; nf < 16; ++nf) {
    float bv = bn1[nf * 16 + l15];
#pragma unroll
    for (int i = 0; i < 4; ++i) {
      float v = acc1[nf][i] + bv;
      acc1[nf][i] = v > 0.f ? v : 0.f;
    }
  }
#pragma unroll
  for (int i = 0; i < 4; ++i) {
    int row = base + grp * 4 + i;
    short8v lo, hi;
#pragma unroll
    for (int q = 0; q < 8; ++q) {
      lo[q] = f2bs(acc1[q][i]);
      hi[q] = f2bs(acc1[q + 8][i]);
    }
    *(short8v*)&t16[row * 264 + l15 * 16] = lo;
    *(short8v*)&t16[row * 264 + l15 * 16 + 8] = hi;
  }
  short8v a2all[12];
  const short* myrow = &t16[(base + l15) * 264];
#pragma unroll
  for (int s = 0; s < 8; ++s)
    a2all[s] = *(const short8v*)(myrow + s * 32 + grp * 8);
#pragma unroll
  for (int c = 4; c < 6; ++c) {
#pragma unroll
    for (int kki = 0; kki < 2; ++kki) {
      int k = (c - 4) * 64 + kki * 32 + grp * 8;
      const float* p = agg2f + (size_t)arow * 128 + k;
      float4 f0 = *(const float4*)p;
      float4 f1 = *(const float4*)(p + 4);
      short8v t;
      t[0] = f2bs(f0.x * inv); t[1] = f2bs(f0.y * inv);
      t[2] = f2bs(f0.z * inv); t[3] = f2bs(f0.w * inv);
      t[4] = f2bs(f1.x * inv); t[5] = f2bs(f1.y * inv);
      t[6] = f2bs(f1.z * inv); t[7] = f2bs(f1.w * inv);
      a2all[c * 2 + kki] = t;
    }
  }
  short8v w2r[24];
#pragma unroll
  for (int c = 0; c < 6; ++c)
#pragma unroll
    for (int s = 0; s < 4; ++s)
      w2r[c * 4 + s] = *(const short8v*)((const short*)Wn2b +
                                         (size_t)(n0w + s * 32) * 384 + c * 64 + cgw * 8);

  f32x4 acc2[8] = {};
#pragma unroll
  for (int c = 0; c < 6; ++c) {
    __syncthreads();
#pragma unroll
    for (int s = 0; s < 4; ++s) {
      int n = n0w + s * 32;
      *(short8v*)(smem_w + n * 128 + ((cgw * 16) ^ ((n & 7) << 4))) = w2r[c * 4 + s];
    }
    __syncthreads();
#pragma unroll
    for (int kki = 0; kki < 2; ++kki) {
#pragma unroll
      for (int nf = 0; nf < 8; ++nf) {
        int wrow = nf * 16 + l15;
        short8v b8 = *(const short8v*)(smem_w + wrow * 128 +
                                       (((kki * 64) + grp * 16) ^ ((wrow & 7) << 4)));
        acc2[nf] = __builtin_amdgcn_mfma_f32_16x16x32_bf16(a2all[c * 2 + kki], b8,
                                                           acc2[nf], 0, 0, 0);
      }
    }
  }

  float* tf32 = (float*)t16;
  int gidr[4];
#pragma unroll
  for (int i = 0; i < 4; ++i) gidr[i] = rowgid_s[base + grp * 4 + i];
#pragma unroll
  for (int nf = 0; nf < 8; ++nf) {
    int col = nf * 16 + l15;
    float bv = bn2[col];
#pragma unroll
    for (int i = 0; i < 4; ++i) {
      float v = acc2[nf][i] + bv + g2n[gidr[i] * 128 + col];
      acc2[nf][i] = v > 0.f ? v : 0.f;
    }
  }
#pragma unroll
  for (int i = 0; i < 4; ++i) {
    int row = base + grp * 4 + i;
    float4 lo = {acc2[0][i], acc2[1][i], acc2[2][i], acc2[3][i]};
    float4 hi = {acc2[4][i], acc2[5][i], acc2[6][i], acc2[7][i]};
    *(float4*)&tf32[row * 132 + l15 * 8] = lo;
    *(float4*)&tf32[row * 132 + l15 * 8 + 4] = hi;
  }
  __syncthreads();

  bool gb = (lane == 63) || (rowgid_s[lane + 1] != rowgid_s[lane]);
  unsigned long long gmask = __ballot(gb);
  if (tid < 128) {
    int col = ((tid & 7) << 4) | (tid >> 3);  // pi2(tid)
    float rn_ = 0.f, re_ = 0.f;
#pragma unroll
    for (int rb = 0; rb < 64; rb += 16) {
      float vn[16], ve[16];
#pragma unroll
      for (int i = 0; i < 16; ++i) {
        int r = rb + i;
        long row = (long)r0 + r;
        bool ok = row < N_NODES;
        vn[i] = ok ? tf32[r * 132 + tid] : 0.f;
        ve[i] = ok ? agg2f[(size_t)row * 128 + col] : 0.f;
      }
#pragma unroll
      for (int i = 0; i < 16; ++i) {
        int r = rb + i;
        rn_ += vn[i];
        re_ += ve[i];
        if ((gmask >> r) & 1) {
          int g = rowgid_s[r];
          atomicAdd(&node_sum[g * 128 + col], rn_);
          atomicAdd(&edge_sum[g * 128 + col], re_);
          rn_ = 0.f;
          re_ = 0.f;
        }
      }
    }
  }
}

// ---------------------------------------------------------------------------
// K7: out = node_avg @ Wgn.T + edge_avg @ Wge.T + gg   [16,128]
__global__ __launch_bounds__(128) void k_final(
    const float* __restrict__ node_sum, const float* __restrict__ edge_sum,
    const int* __restrict__ node_cnt_g, const int* __restrict__ edge_cnt_g,
    const float* __restrict__ Wgn, const float* __restrict__ Wge,
    const float* __restrict__ gg, float* __restrict__ out) {
  __shared__ float navg[128], eavg[128];
  const int g = blockIdx.x, c = threadIdx.x;
  int nc = node_cnt_g[g];
  nc = nc > 1 ? nc : 1;
  int ec = edge_cnt_g[g];
  ec = ec > 1 ? ec : 1;
  navg[c] = node_sum[g * 128 + c] / (float)nc;
  eavg[c] = edge_sum[g * 128 + c] / (float)ec;
  __syncthreads();
  float acc = gg[g * 128 + c];
#pragma unroll 4
  for (int k = 0; k < 128; ++k)
    acc += navg[k] * Wgn[c * 128 + k] + eavg[k] * Wge[c * 128 + k];
  out[g * 128 + c] = acc;
}

// ---------------------------------------------------------------------------
extern "C" void kernel_launch(void* const* d_in, const int* in_sizes, int n_in,
                              void* d_out, int out_size, void* d_ws, size_t ws_size,
                              hipStream_t stream) {
  const float* node_feats = (const float*)d_in[0];
  const float* edge_feats = (const float*)d_in[1];
  const float* globals_ = (const float*)d_in[2];
  const float* We1 = (const float*)d_in[3];
  const float* be1 = (const float*)d_in[4];
  const float* Wn1 = (const float*)d_in[5];
  const float* Win1 = (const float*)d_in[6];
  const float* bn1 = (const float*)d_in[7];
  const float* We2 = (const float*)d_in[8];
  const float* Wg2 = (const float*)d_in[9];
  const float* be2 = (const float*)d_in[10];
  const float* Wn2 = (const float*)d_in[11];
  const float* Win2 = (const float*)d_in[12];
  const float* Wng2 = (const float*)d_in[13];
  const float* bn2 = (const float*)d_in[14];
  const float* Wgn = (const float*)d_in[15];
  const float* Wge = (const float*)d_in[16];
  const float* Wgg = (const float*)d_in[17];
  const float* bg = (const float*)d_in[18];
  const int* receivers = (const int*)d_in[19];
  const int* node_graph = (const int*)d_in[20];
  float* out = (float*)d_out;

  char* ws = (char*)d_ws;
  size_t off = 0;
  auto alloc = [&](size_t bytes) {
    size_t o = off;
    off += (bytes + 255) & ~(size_t)255;
    return o;
  };
  const int NP = 20032;  // N_NODES padded to 64
  // --- zero region (accumulators) ---
  int* cnt_node = (int*)(ws + alloc((size_t)N_NODES * 4));
  int* node_cnt_g = (int*)(ws + alloc(NG * 4));
  int* edge_cnt_g = (int*)(ws + alloc(NG * 4));
  float* node_sum = (float*)(ws + alloc(NG * 128 * 4));
  float* edge_sum = (float*)(ws + alloc(NG * 128 * 4));
  float* agg1f = (float*)(ws + alloc((size_t)N_NODES * 256 * 4));
  float* agg2f = (float*)(ws + alloc((size_t)N_NODES * 128 * 4));
  size_t zero_bytes = off;
  // --- rewritten every call ---
  int* offset = (int*)(ws + alloc((size_t)(N_NODES + 1) * 4));
  int* cursor = (int*)(ws + alloc((size_t)N_NODES * 4));
  int* pos2edge = (int*)(ws + alloc((size_t)N_EDGES * 4));
  int* pos2node = (int*)(ws + alloc((size_t)N_EDGES * 4));
  float* g2e = (float*)(ws + alloc(NG * 128 * 4));
  float* g2n = (float*)(ws + alloc(NG * 128 * 4));
  float* gg = (float*)(ws + alloc(NG * 128 * 4));
  bf16* Wb_e1 = (bf16*)(ws + alloc(8192 * 2));
  bf16* Wb_n1 = (bf16*)(ws + alloc(81920 * 2));
  bf16* Wb_e2 = (bf16*)(ws + alloc(32768 * 2));
  bf16* Wb_n2 = (bf16*)(ws + alloc(49152 * 2));
  bf16* nfb = (bf16*)(ws + alloc((size_t)NP * 64 * 2));
  (void)ws_size;

  hipMemsetAsync(d_ws, 0, zero_bytes, stream);
  k_prep<<<1946, 256, 0, stream>>>(globals_, Wg2, Wng2, Wgg, bg, g2e, g2n, gg,
                                   We1, Wn1, Win1, We2, Wn2, Win2, Wb_e1,
                                   Wb_n1, Wb_e2, Wb_n2, node_feats, nfb);
  k_counts<<<(N_EDGES + N_NODES + 255) / 256, 256, 0, stream>>>(
      receivers, node_graph, cnt_node, node_cnt_g, edge_cnt_g);
  k_scan<<<1, 256, 0, stream>>>(cnt_node, offset, cursor);
  k_scatter<<<(N_EDGES + 255) / 256, 256, 0, stream>>>(receivers, offset,
                                                       cursor, pos2edge,
                                                       pos2node);
  k_edge<<<N_EDGES / 64, 256, 0, stream>>>(edge_feats, Wb_e1, Wb_e2, be1, be2,
                                           g2e, pos2edge, pos2node, node_graph,
                                           offset, agg1f, agg2f);
  k_node<<<NP / 64, 256, 0, stream>>>(nfb, agg1f, agg2f, offset, Wb_n1, Wb_n2,
                                      bn1, bn2, g2n, node_graph, node_sum,
                                      edge_sum);
  k_final<<<NG, 128, 0, stream>>>(node_sum, edge_sum, node_cnt_g, edge_cnt_g,
                                  Wgn, Wge, gg, out);
}